// Round 9
// baseline (393.144 us; speedup 1.0000x reference)
//
#include <hip/hip_runtime.h>

#define NB   4
#define SXX  4096
#define SLL  256
#define DD   1024
#define HH   16
#define DHH  64
#define SKV  4352      // SX + SL
#define MKV  17408     // NB * SKV
#define NSPLIT 8

typedef __attribute__((ext_vector_type(8))) short bfrag;   // 8 bf16 (4 VGPRs), MFMA A/B frag
typedef __attribute__((ext_vector_type(4))) float facc;    // MFMA 16x16 C/D frag

__device__ __forceinline__ unsigned short f2bf(float f){
  unsigned u = __builtin_bit_cast(unsigned, f);
  u = (u + 0x7fffu + ((u >> 16) & 1u)) >> 16;   // RNE
  return (unsigned short)u;
}
__device__ __forceinline__ float bf2f(unsigned short h){
  unsigned u = ((unsigned)h) << 16;
  return __builtin_bit_cast(float, u);
}

#define GLOAD_LDS16(g, lds) __builtin_amdgcn_global_load_lds( \
    (const __attribute__((address_space(1))) unsigned int*)(const void*)(g), \
    (__attribute__((address_space(3))) unsigned int*)(void*)(lds), 16, 0, 0)

// ---- weights: in[K][N] f32 -> out[N][K] bf16 ; all three in one launch (grid.z)
__global__ void wtrans3(const float* __restrict__ Wq, const float* __restrict__ Wkv,
                        const float* __restrict__ Wo, unsigned short* __restrict__ wqt,
                        unsigned short* __restrict__ wkvt, unsigned short* __restrict__ wot){
  __shared__ float t[32][33];
  int z = blockIdx.z;
  const float* in; unsigned short* out; int N;
  if (z == 0){ in = Wq;  out = wqt;  N = DD;   }
  else if (z == 1){ in = Wkv; out = wkvt; N = 2*DD; }
  else { in = Wo;  out = wot;  N = DD;   }
  int n0 = blockIdx.x * 32, k0 = blockIdx.y * 32;
  if (n0 >= N) return;
  int tx = threadIdx.x, ty = threadIdx.y;
  #pragma unroll
  for (int i = 0; i < 4; i++)
    t[ty + 8*i][tx] = in[(size_t)(k0 + ty + 8*i) * N + n0 + tx];
  __syncthreads();
  #pragma unroll
  for (int i = 0; i < 4; i++)
    out[(size_t)(n0 + ty + 8*i) * DD + k0 + tx] = f2bf(t[tx][ty + 8*i]);
}

// ---- layernorm (x and latents in ONE launch): row over [B][SKV]
__global__ void lnorm_all(const float* __restrict__ x, const float* __restrict__ latents,
                          const float* __restrict__ gx, const float* __restrict__ bx,
                          const float* __restrict__ gl, const float* __restrict__ bl,
                          unsigned short* __restrict__ kvin, unsigned short* __restrict__ lnlat){
  int r = blockIdx.x;
  int b = r / SKV, s = r - b*SKV;
  bool lat = (s >= SXX);
  const float* src = lat ? latents + (size_t)(b*SLL + s - SXX) * DD
                         : x       + (size_t)(b*SXX + s) * DD;
  const float* g  = lat ? gl : gx;
  const float* bt = lat ? bl : bx;
  int t = threadIdx.x;
  float4 v = ((const float4*)src)[t];
  float sum = v.x + v.y + v.z + v.w;
  float sq  = v.x*v.x + v.y*v.y + v.z*v.z + v.w*v.w;
  #pragma unroll
  for (int o = 32; o > 0; o >>= 1){ sum += __shfl_down(sum, o); sq += __shfl_down(sq, o); }
  __shared__ float ls[8];
  int w = t >> 6, l = t & 63;
  if (l == 0){ ls[w] = sum; ls[4 + w] = sq; }
  __syncthreads();
  sum = ls[0] + ls[1] + ls[2] + ls[3];
  sq  = ls[4] + ls[5] + ls[6] + ls[7];
  float mu  = sum * (1.f/DD);
  float var = sq * (1.f/DD) - mu*mu;
  float rs  = rsqrtf(var + 1e-5f);
  float4 gv = ((const float4*)g)[t];
  float4 bv = ((const float4*)bt)[t];
  ushort4 o4;
  o4.x = f2bf((v.x - mu)*rs*gv.x + bv.x);
  o4.y = f2bf((v.y - mu)*rs*gv.y + bv.y);
  o4.z = f2bf((v.z - mu)*rs*gv.z + bv.z);
  o4.w = f2bf((v.w - mu)*rs*gv.w + bv.w);
  *(ushort4*)(kvin + (size_t)r * DD + t*4) = o4;
  if (lat) *(ushort4*)(lnlat + (size_t)(b*SLL + s - SXX) * DD + t*4) = o4;
}

// ---- small GEMM (o projection): 64x64 tile, 4 waves. A[M][K], Bt[N][K] bf16 -> C f32
__global__ __launch_bounds__(256) void gemm64(const unsigned short* __restrict__ A,
    const unsigned short* __restrict__ Bt, int M, int N, int K, float* __restrict__ outF){
  __shared__ unsigned short lA[64][72];
  __shared__ unsigned short lB[64][72];
  int n0 = blockIdx.x * 64, m0 = blockIdx.y * 64;
  int t = threadIdx.x, w = t >> 6, l = t & 63;
  int wr = (w >> 1) * 32, wc = (w & 1) * 32;
  int lr = l & 15, kq = (l >> 4) * 8;
  facc acc00 = (facc)0.f, acc01 = (facc)0.f, acc10 = (facc)0.f, acc11 = (facc)0.f;
  for (int k0 = 0; k0 < K; k0 += 64){
    #pragma unroll
    for (int cc = 0; cc < 2; cc++){
      int ch = t + cc*256;
      int row = ch >> 3, cg = (ch & 7) * 8;
      *(bfrag*)&lA[row][cg] = *(const bfrag*)&A[(size_t)(m0 + row) * K + k0 + cg];
      *(bfrag*)&lB[row][cg] = *(const bfrag*)&Bt[(size_t)(n0 + row) * K + k0 + cg];
    }
    __syncthreads();
    #pragma unroll
    for (int ks = 0; ks < 2; ks++){
      bfrag a0 = *(const bfrag*)&lA[wr + lr][ks*32 + kq];
      bfrag a1 = *(const bfrag*)&lA[wr + 16 + lr][ks*32 + kq];
      bfrag b0 = *(const bfrag*)&lB[wc + lr][ks*32 + kq];
      bfrag b1 = *(const bfrag*)&lB[wc + 16 + lr][ks*32 + kq];
      acc00 = __builtin_amdgcn_mfma_f32_16x16x32_bf16(a0, b0, acc00, 0, 0, 0);
      acc01 = __builtin_amdgcn_mfma_f32_16x16x32_bf16(a0, b1, acc01, 0, 0, 0);
      acc10 = __builtin_amdgcn_mfma_f32_16x16x32_bf16(a1, b0, acc10, 0, 0, 0);
      acc11 = __builtin_amdgcn_mfma_f32_16x16x32_bf16(a1, b1, acc11, 0, 0, 0);
    }
    __syncthreads();
  }
  int rl = (l >> 4) * 4, cl = l & 15;
  facc accs[2][2] = {{acc00, acc01},{acc10, acc11}};
  #pragma unroll
  for (int mt = 0; mt < 2; mt++)
  #pragma unroll
  for (int nt = 0; nt < 2; nt++)
  #pragma unroll
  for (int j = 0; j < 4; j++){
    int r = m0 + wr + mt*16 + rl + j;
    int c = n0 + wc + nt*16 + cl;
    outF[(size_t)r * N + c] = accs[mt][nt][j];
  }
}

// ---- q GEMM with FUSED rmsnorm+gamma^2+1/8 epilogue -> qnb bf16 [B][H][SL][DH]
__global__ __launch_bounds__(256) void gemm_q(const unsigned short* __restrict__ A,
    const unsigned short* __restrict__ Bt, const float* __restrict__ gamma,
    unsigned short* __restrict__ qn){
  __shared__ char smemb[18432];          // lA/lB (2x 64x72 shorts) ; reused as Cf f32[64][66]
  unsigned short* lA = (unsigned short*)smemb;
  unsigned short* lB = lA + 64*72;
  float* Cf = (float*)smemb;             // 64*66*4 = 16896 <= 18432
  int h = blockIdx.x, n0 = h * 64, m0 = blockIdx.y * 64;
  int t = threadIdx.x, w = t >> 6, l = t & 63;
  int wr = (w >> 1) * 32, wc = (w & 1) * 32;
  int lr = l & 15, kq = (l >> 4) * 8;
  facc acc00 = (facc)0.f, acc01 = (facc)0.f, acc10 = (facc)0.f, acc11 = (facc)0.f;
  for (int k0 = 0; k0 < 1024; k0 += 64){
    #pragma unroll
    for (int cc = 0; cc < 2; cc++){
      int ch = t + cc*256;
      int row = ch >> 3, cg = (ch & 7) * 8;
      *(bfrag*)&lA[row*72 + cg] = *(const bfrag*)&A[(size_t)(m0 + row) * 1024 + k0 + cg];
      *(bfrag*)&lB[row*72 + cg] = *(const bfrag*)&Bt[(size_t)(n0 + row) * 1024 + k0 + cg];
    }
    __syncthreads();
    #pragma unroll
    for (int ks = 0; ks < 2; ks++){
      bfrag a0 = *(const bfrag*)&lA[(wr + lr)*72 + ks*32 + kq];
      bfrag a1 = *(const bfrag*)&lA[(wr + 16 + lr)*72 + ks*32 + kq];
      bfrag b0 = *(const bfrag*)&lB[(wc + lr)*72 + ks*32 + kq];
      bfrag b1 = *(const bfrag*)&lB[(wc + 16 + lr)*72 + ks*32 + kq];
      acc00 = __builtin_amdgcn_mfma_f32_16x16x32_bf16(a0, b0, acc00, 0, 0, 0);
      acc01 = __builtin_amdgcn_mfma_f32_16x16x32_bf16(a0, b1, acc01, 0, 0, 0);
      acc10 = __builtin_amdgcn_mfma_f32_16x16x32_bf16(a1, b0, acc10, 0, 0, 0);
      acc11 = __builtin_amdgcn_mfma_f32_16x16x32_bf16(a1, b1, acc11, 0, 0, 0);
    }
    __syncthreads();
  }
  int rl = (l >> 4) * 4, cl = l & 15;
  facc accs[2][2] = {{acc00, acc01},{acc10, acc11}};
  #pragma unroll
  for (int mt = 0; mt < 2; mt++)
  #pragma unroll
  for (int nt = 0; nt < 2; nt++)
  #pragma unroll
  for (int j = 0; j < 4; j++)
    Cf[(wr + mt*16 + rl + j)*66 + wc + nt*16 + cl] = accs[mt][nt][j];
  __syncthreads();
  if (t < 64){
    const float* src = &Cf[t*66];
    float ss = 0.f;
    #pragma unroll
    for (int d = 0; d < 64; d++){ float a = src[d]; ss = fmaf(a, a, ss); }
    float rv = 0.125f / fmaxf(sqrtf(ss) * 0.125f, 1e-8f);
    int r = m0 + t, b = r >> 8, sl = r & 255;
    unsigned short* dst = &qn[((size_t)(b*HH + h)*SLL + sl)*DHH];
    #pragma unroll
    for (int i = 0; i < 8; i++){
      ushort4 p; float g;
      g = gamma[i*8+0]; p.x = f2bf(src[i*8+0]*g*g*rv);
      g = gamma[i*8+1]; p.y = f2bf(src[i*8+1]*g*g*rv);
      g = gamma[i*8+2]; p.z = f2bf(src[i*8+2]*g*g*rv);
      g = gamma[i*8+3]; p.w = f2bf(src[i*8+3]*g*g*rv);
      ushort4 q;
      g = gamma[i*8+4]; q.x = f2bf(src[i*8+4]*g*g*rv);
      g = gamma[i*8+5]; q.y = f2bf(src[i*8+5]*g*g*rv);
      g = gamma[i*8+6]; q.z = f2bf(src[i*8+6]*g*g*rv);
      g = gamma[i*8+7]; q.w = f2bf(src[i*8+7]*g*g*rv);
      *(ushort4*)&dst[i*8]     = p;
      *(ushort4*)&dst[i*8 + 4] = q;
    }
  }
}

// ---- kv GEMM, m97 structure, R7 epilogue + rkm SCALAR store (no 64-elem rescale chain:
// R8's 320-op lockstep epilogue cost +14us; this keeps only the ~130-op ss computation).
__global__ __launch_bounds__(256) void gemm_kv(const unsigned short* __restrict__ A,
    const unsigned short* __restrict__ Bt,
    unsigned short* __restrict__ outK, unsigned short* __restrict__ outV,
    float* __restrict__ rkm){
  __shared__ unsigned short smem[128*136];   // 34816 B; K-loop uses first 2*128*64
  unsigned short* lA = smem;
  unsigned short* lB = smem + 128*64;
  int n0 = blockIdx.x * 128, m0 = blockIdx.y * 128;
  int t = threadIdx.x, w = t >> 6, l = t & 63;
  int wr = (w >> 1) * 64, wc = (w & 1) * 64;
  int lr = l & 15, q2 = l >> 4;
  int r8 = l >> 3, u = l & 7;
  facc acc[4][4];
  #pragma unroll
  for (int mt = 0; mt < 4; mt++)
  #pragma unroll
  for (int nt = 0; nt < 4; nt++) acc[mt][nt] = (facc)0.f;
  const unsigned short* Ab = A  + (size_t)(m0 + w*32 + r8) * 1024 + (u ^ (r8 & 7)) * 8;
  const unsigned short* Bb = Bt + (size_t)(n0 + w*32 + r8) * 1024 + (u ^ (r8 & 7)) * 8;
  for (int k0 = 0; k0 < 1024; k0 += 64){
    #pragma unroll
    for (int i = 0; i < 4; i++){
      GLOAD_LDS16(Ab + (size_t)i*8*1024 + k0, &lA[(w*32 + i*8)*64]);
      GLOAD_LDS16(Bb + (size_t)i*8*1024 + k0, &lB[(w*32 + i*8)*64]);
    }
    __syncthreads();
    #pragma unroll
    for (int ks = 0; ks < 2; ks++){
      int su = ((ks*4 + q2) ^ (lr & 7)) * 8;
      bfrag av[4], bv[4];
      #pragma unroll
      for (int mt = 0; mt < 4; mt++) av[mt] = *(const bfrag*)&lA[(wr + mt*16 + lr)*64 + su];
      #pragma unroll
      for (int nt = 0; nt < 4; nt++) bv[nt] = *(const bfrag*)&lB[(wc + nt*16 + lr)*64 + su];
      #pragma unroll
      for (int mt = 0; mt < 4; mt++)
      #pragma unroll
      for (int nt = 0; nt < 4; nt++)
        acc[mt][nt] = __builtin_amdgcn_mfma_f32_16x16x32_bf16(av[mt], bv[nt], acc[mt][nt], 0, 0, 0);
    }
    __syncthreads();
  }
  // epilogue: tiles never span batches (SKV = 34*128)
  int b = m0 / SKV, s0 = m0 - b*SKV;
  int rl = q2 * 4;
  if (blockIdx.x < 8){
    // K half: stage [s][c] (pad 136), per-thread full 128B line; ss (2 chains) -> rkm scalar
    #pragma unroll
    for (int mt = 0; mt < 4; mt++)
    #pragma unroll
    for (int nt = 0; nt < 4; nt++)
    #pragma unroll
    for (int j = 0; j < 4; j++)
      smem[(wr + mt*16 + rl + j)*136 + wc + nt*16 + lr] = f2bf(acc[mt][nt][j]);
    __syncthreads();
    int s = t >> 1, hf = t & 1;
    const unsigned short* src = &smem[s*136 + hf*64];
    uint4 wv[8];
    #pragma unroll
    for (int i = 0; i < 8; i++) wv[i] = *(const uint4*)&src[i*8];
    float ss0 = 0.f, ss1 = 0.f;
    #pragma unroll
    for (int i = 0; i < 8; i++){
      const unsigned short* pp = (const unsigned short*)&wv[i];
      #pragma unroll
      for (int e = 0; e < 4; e++){
        float a = bf2f(pp[e]);     ss0 = fmaf(a, a, ss0);
        float c = bf2f(pp[e + 4]); ss1 = fmaf(c, c, ss1);
      }
    }
    float rv = 1.f / fmaxf(sqrtf(ss0 + ss1) * 0.125f, 1e-8f);
    int h = (n0 >> 6) + hf;
    unsigned short* dst = &outK[((size_t)(b*HH + h)*SKV + s0 + s)*DHH];
    #pragma unroll
    for (int i = 0; i < 8; i++)
      *(uint4*)&dst[i*8] = wv[i];
    rkm[((size_t)(b*HH + h))*SKV + s0 + s] = rv;
  } else {
    // V half: stage [c][s] (pad 136; j contiguous -> b64 writes), 128B lines to vT
    #pragma unroll
    for (int mt = 0; mt < 4; mt++)
    #pragma unroll
    for (int nt = 0; nt < 4; nt++){
      ushort4 p;
      p.x = f2bf(acc[mt][nt][0]); p.y = f2bf(acc[mt][nt][1]);
      p.z = f2bf(acc[mt][nt][2]); p.w = f2bf(acc[mt][nt][3]);
      *(ushort4*)&smem[(wc + nt*16 + lr)*136 + wr + mt*16 + rl] = p;
    }
    __syncthreads();
    int c = t >> 1, hf = t & 1;
    int hh = ((n0 - DD) >> 6) + (c >> 6), d = c & 63;
    const unsigned short* src = &smem[c*136 + hf*64];
    unsigned short* dst = &outV[((size_t)(b*HH + hh)*DHH + d)*SKV + s0 + hf*64];
    #pragma unroll
    for (int i = 0; i < 8; i++)
      *(uint4*)&dst[i*8] = *(const uint4*)&src[i*8];
  }
}

// ---- flash attention, split-KV, 2 q-tiles/block, FIXED-MAX softmax.
// After folding, s = q'·k·rkm ∈ [-8, 8] (|gamma|=1), so P = exp(s - 8) needs no online max:
// no max-reduce, no alpha, no O-rescale -> QK->PV serial chain minimized.
__global__ __launch_bounds__(256) void attn(const unsigned short* __restrict__ qn,
    const unsigned short* __restrict__ kbuf, const unsigned short* __restrict__ vT,
    const float* __restrict__ rkm, const float* __restrict__ mask_x,
    const float* __restrict__ mask_lat,
    float* __restrict__ Opart, float* __restrict__ lpart){
  int qt = blockIdx.x, bh = blockIdx.y, split = blockIdx.z;
  int b = bh >> 4;
  __shared__ unsigned short lP[4][2][16][68];   // per-wave, per-tile P staging
  int t = threadIdx.x, w = t >> 6, l = t & 63;
  int lr = l & 15, q2 = l >> 4, kq = q2 * 8;
  int q0 = qt * 128;
  bfrag aq0[2], aq1[2];
  float rm[2][4];
  #pragma unroll
  for (int tt = 0; tt < 2; tt++){
    const unsigned short* qbase = qn + ((size_t)bh * SLL + q0 + tt*64 + w*16 + lr) * DHH;
    aq0[tt] = *(const bfrag*)&qbase[kq];
    aq1[tt] = *(const bfrag*)&qbase[32 + kq];
    #pragma unroll
    for (int j = 0; j < 4; j++) rm[tt][j] = mask_lat[b*SLL + q0 + tt*64 + w*16 + q2*4 + j];
  }
  facc O[2][4];
  #pragma unroll
  for (int tt = 0; tt < 2; tt++)
  #pragma unroll
  for (int nt = 0; nt < 4; nt++) O[tt][nt] = (facc)0.f;
  float lsum[2][4];
  #pragma unroll
  for (int tt = 0; tt < 2; tt++)
  #pragma unroll
  for (int j = 0; j < 4; j++) lsum[tt][j] = 0.f;

  int t0 = (split * 68) / NSPLIT, t1 = ((split + 1) * 68) / NSPLIT;
  for (int kt = t0; kt < t1; kt++){
    int key0 = kt * 64;
    const unsigned short* kb = kbuf + ((size_t)bh * SKV + key0) * DHH;
    bfrag bk0[4], bk1[4]; float rk[4];
    #pragma unroll
    for (int nt = 0; nt < 4; nt++){
      bk0[nt] = *(const bfrag*)&kb[(nt*16 + lr)*DHH + kq];
      bk1[nt] = *(const bfrag*)&kb[(nt*16 + lr)*DHH + 32 + kq];
      int gi = key0 + nt*16 + lr;
      float cm = (gi < SXX) ? mask_x[b*SXX + gi] : mask_lat[b*SLL + gi - SXX];
      float rv = rkm[(size_t)bh*SKV + gi];
      rk[nt] = (cm != 0.f) ? rv : -1.f;    // sentinel: masked key
    }
    facc S[2][4];
    #pragma unroll
    for (int tt = 0; tt < 2; tt++)
    #pragma unroll
    for (int nt = 0; nt < 4; nt++){
      S[tt][nt] = (facc)0.f;
      S[tt][nt] = __builtin_amdgcn_mfma_f32_16x16x32_bf16(aq0[tt], bk0[nt], S[tt][nt], 0, 0, 0);
      S[tt][nt] = __builtin_amdgcn_mfma_f32_16x16x32_bf16(aq1[tt], bk1[nt], S[tt][nt], 0, 0, 0);
    }
    #pragma unroll
    for (int tt = 0; tt < 2; tt++){
      #pragma unroll
      for (int j = 0; j < 4; j++){
        float rs_ = 0.f;
        #pragma unroll
        for (int nt = 0; nt < 4; nt++){
          float x = S[tt][nt][j] * rk[nt];
          float sv = (rk[nt] >= 0.f && rm[tt][j] != 0.f) ? x : -3.0e38f;
          float p = __expf(sv - 8.0f);
          rs_ += p;
          lP[w][tt][q2*4 + j][nt*16 + lr] = f2bf(p);
        }
        lsum[tt][j] += rs_;   // per-lane partial (16-lane reduce deferred)
      }
    }
    __asm__ volatile("s_waitcnt lgkmcnt(0)" ::: "memory");   // wave-private LDS round trip
    bfrag ap0[2], ap1[2];
    #pragma unroll
    for (int tt = 0; tt < 2; tt++){
      ap0[tt] = *(const bfrag*)&lP[w][tt][lr][kq];
      ap1[tt] = *(const bfrag*)&lP[w][tt][lr][32 + kq];
    }
    const unsigned short* vb = vT + (size_t)bh * DHH * SKV + key0;
    #pragma unroll
    for (int nt = 0; nt < 4; nt++){
      bfrag bv0 = *(const bfrag*)&vb[(size_t)(nt*16 + lr)*SKV + kq];
      bfrag bv1 = *(const bfrag*)&vb[(size_t)(nt*16 + lr)*SKV + 32 + kq];
      #pragma unroll
      for (int tt = 0; tt < 2; tt++){
        O[tt][nt] = __builtin_amdgcn_mfma_f32_16x16x32_bf16(ap0[tt], bv0, O[tt][nt], 0, 0, 0);
        O[tt][nt] = __builtin_amdgcn_mfma_f32_16x16x32_bf16(ap1[tt], bv1, O[tt][nt], 0, 0, 0);
      }
    }
  }
  #pragma unroll
  for (int tt = 0; tt < 2; tt++)
  #pragma unroll
  for (int j = 0; j < 4; j++){
    float L = lsum[tt][j];
    L += __shfl_xor(L, 1); L += __shfl_xor(L, 2);
    L += __shfl_xor(L, 4); L += __shfl_xor(L, 8);
    int srow = q0 + tt*64 + w*16 + q2*4 + j;
    size_t obase = (((size_t)split*64 + bh)*SLL + srow)*DHH;
    #pragma unroll
    for (int nt = 0; nt < 4; nt++)
      Opart[obase + nt*16 + lr] = O[tt][nt][j];
    if (lr == 0)
      lpart[((size_t)split*64 + bh)*SLL + srow] = L;
  }
}

// ---- combine partials across splits (fixed-max: plain sums) -> ybuf bf16 [B][SL][D]
__global__ __launch_bounds__(256) void attn_combine(const float* __restrict__ Opart,
    const float* __restrict__ lpart, unsigned short* __restrict__ ybuf){
  int t = threadIdx.x, w = t >> 6, l = t & 63;
  int idx = blockIdx.x * 4 + w;
  int bh = idx >> 8, srow = idx & 255;
  int b = bh >> 4, h = bh & 15;
  float L = 0.f, acc = 0.f;
  #pragma unroll
  for (int s = 0; s < NSPLIT; s++){
    L   += lpart[((size_t)s*64 + bh)*SLL + srow];
    acc += Opart[(((size_t)s*64 + bh)*SLL + srow)*DHH + l];
  }
  ybuf[((size_t)b*SLL + srow)*DD + h*DHH + l] = f2bf(acc / L);
}

extern "C" void kernel_launch(void* const* d_in, const int* in_sizes, int n_in,
                              void* d_out, int out_size, void* d_ws, size_t ws_size,
                              hipStream_t stream) {
  const float* x        = (const float*)d_in[0];
  const float* latents  = (const float*)d_in[1];
  const float* mask_x   = (const float*)d_in[2];
  const float* mask_lat = (const float*)d_in[3];
  const float* ln_x_g   = (const float*)d_in[4];
  const float* ln_x_b   = (const float*)d_in[5];
  const float* ln_l_g   = (const float*)d_in[6];
  const float* ln_l_b   = (const float*)d_in[7];
  const float* Wq       = (const float*)d_in[8];
  const float* Wkv      = (const float*)d_in[9];
  const float* qk_gamma = (const float*)d_in[10];
  const float* Wo       = (const float*)d_in[11];
  float* out = (float*)d_out;

  // ws layout (~127 MB). Opart/lpart ALIAS kvin/lnlat (dead once attn runs).
  char* wsb = (char*)d_ws;
  unsigned short* kvin  = (unsigned short*)(wsb + 0);          // [MKV][D] bf16       35651584
  unsigned short* lnlat = (unsigned short*)(wsb + 35651584);   // [B*SL][D] bf16       2097152
  unsigned short* wqt   = (unsigned short*)(wsb + 37748736);   // [D][D] bf16          2097152
  unsigned short* wkvt  = (unsigned short*)(wsb + 39845888);   // [2D][D] bf16         4194304
  unsigned short* wot   = (unsigned short*)(wsb + 44040192);   // [D][D] bf16          2097152
  unsigned short* qnb   = (unsigned short*)(wsb + 50331648);   // [B][H][SL][DH]       2097152
  unsigned short* kbuf  = (unsigned short*)(wsb + 52428800);   // [B][H][SKV][DH]     35651584
  unsigned short* vT    = (unsigned short*)(wsb + 88080384);   // [B][H][DH][SKV]     35651584
  float*          rkm   = (float*)(wsb + 123731968);           // [B*H*SKV] f32        1114112
  unsigned short* ybuf  = (unsigned short*)(wsb + 124846080);  // [B*SL][D] bf16       2097152
  float*          Opart = (float*)(wsb + 0);                   // [8][64][256][64] f32 33554432 (alias kvin)
  float*          lpart = (float*)(wsb + 35651584);            // [8][64][256] f32      524288 (alias lnlat)

  wtrans3<<<dim3(64, 32, 3), dim3(32, 8), 0, stream>>>(Wq, Wkv, Wo, wqt, wkvt, wot);

  lnorm_all<<<NB*SKV, 256, 0, stream>>>(x, latents, ln_x_g, ln_x_b, ln_l_g, ln_l_b, kvin, lnlat);

  gemm_q<<<dim3(16, 16), 256, 0, stream>>>(lnlat, wqt, qk_gamma, qnb);
  gemm_kv<<<dim3(16, 136), 256, 0, stream>>>(kvin, wkvt, kbuf, vT, rkm);

  attn<<<dim3(SLL/128, NB*HH, NSPLIT), 256, 0, stream>>>(qnb, kbuf, vT, rkm, mask_x, mask_lat, Opart, lpart);
  attn_combine<<<(NB*HH*SLL)/4, 256, 0, stream>>>(Opart, lpart, ybuf);

  gemm64<<<dim3(DD/64, (NB*SLL)/64), 256, 0, stream>>>(ybuf, wot, NB*SLL, DD, DD, out);
}

// Round 10
// 374.475 us; speedup vs baseline: 1.0499x; 1.0499x over previous
//
#include <hip/hip_runtime.h>

#define NB   4
#define SXX  4096
#define SLL  256
#define DD   1024
#define HH   16
#define DHH  64
#define SKV  4352      // SX + SL
#define MKV  17408     // NB * SKV
#define NSPLIT 8

typedef __attribute__((ext_vector_type(8))) short bfrag;   // 8 bf16 (4 VGPRs), MFMA A/B frag
typedef __attribute__((ext_vector_type(4))) float facc;    // MFMA 16x16 C/D frag

__device__ __forceinline__ unsigned short f2bf(float f){
  unsigned u = __builtin_bit_cast(unsigned, f);
  u = (u + 0x7fffu + ((u >> 16) & 1u)) >> 16;   // RNE
  return (unsigned short)u;
}
__device__ __forceinline__ float bf2f(unsigned short h){
  unsigned u = ((unsigned)h) << 16;
  return __builtin_bit_cast(float, u);
}

#define GLOAD_LDS16(g, lds) __builtin_amdgcn_global_load_lds( \
    (const __attribute__((address_space(1))) unsigned int*)(const void*)(g), \
    (__attribute__((address_space(3))) unsigned int*)(void*)(lds), 16, 0, 0)

// ---- weights: in[K][N] f32 -> out[N][K] bf16 ; all three in one launch (grid.z)
__global__ void wtrans3(const float* __restrict__ Wq, const float* __restrict__ Wkv,
                        const float* __restrict__ Wo, unsigned short* __restrict__ wqt,
                        unsigned short* __restrict__ wkvt, unsigned short* __restrict__ wot){
  __shared__ float t[32][33];
  int z = blockIdx.z;
  const float* in; unsigned short* out; int N;
  if (z == 0){ in = Wq;  out = wqt;  N = DD;   }
  else if (z == 1){ in = Wkv; out = wkvt; N = 2*DD; }
  else { in = Wo;  out = wot;  N = DD;   }
  int n0 = blockIdx.x * 32, k0 = blockIdx.y * 32;
  if (n0 >= N) return;
  int tx = threadIdx.x, ty = threadIdx.y;
  #pragma unroll
  for (int i = 0; i < 4; i++)
    t[ty + 8*i][tx] = in[(size_t)(k0 + ty + 8*i) * N + n0 + tx];
  __syncthreads();
  #pragma unroll
  for (int i = 0; i < 4; i++)
    out[(size_t)(n0 + ty + 8*i) * DD + k0 + tx] = f2bf(t[tx][ty + 8*i]);
}

// ---- layernorm one row (D=1024) -> bf16 into kvin (+ optional second copy)
__global__ void lnorm(const float* __restrict__ src, const float* __restrict__ g,
                      const float* __restrict__ bt, unsigned short* __restrict__ kvin,
                      unsigned short* __restrict__ dst2, int seq, int off){
  int row = blockIdx.x;
  int b = row / seq, s = row - b*seq;
  int t = threadIdx.x;
  const float4* rp = (const float4*)(src + (size_t)row * DD);
  float4 v = rp[t];
  float sum = v.x + v.y + v.z + v.w;
  float sq  = v.x*v.x + v.y*v.y + v.z*v.z + v.w*v.w;
  #pragma unroll
  for (int o = 32; o > 0; o >>= 1){ sum += __shfl_down(sum, o); sq += __shfl_down(sq, o); }
  __shared__ float ls[8];
  int w = t >> 6, l = t & 63;
  if (l == 0){ ls[w] = sum; ls[4 + w] = sq; }
  __syncthreads();
  sum = ls[0] + ls[1] + ls[2] + ls[3];
  sq  = ls[4] + ls[5] + ls[6] + ls[7];
  float mu  = sum * (1.f/DD);
  float var = sq * (1.f/DD) - mu*mu;
  float rs  = rsqrtf(var + 1e-5f);
  float4 gv = ((const float4*)g)[t];
  float4 bv = ((const float4*)bt)[t];
  ushort4 o4;
  o4.x = f2bf((v.x - mu)*rs*gv.x + bv.x);
  o4.y = f2bf((v.y - mu)*rs*gv.y + bv.y);
  o4.z = f2bf((v.z - mu)*rs*gv.z + bv.z);
  o4.w = f2bf((v.w - mu)*rs*gv.w + bv.w);
  *(ushort4*)(kvin + (size_t)(b*SKV + off + s) * DD + t*4) = o4;
  if (dst2) *(ushort4*)(dst2 + (size_t)row * DD + t*4) = o4;
}

// ---- small GEMM (o projection): 64x64 tile, 4 waves. A[M][K], Bt[N][K] bf16 -> C f32
__global__ __launch_bounds__(256) void gemm64(const unsigned short* __restrict__ A,
    const unsigned short* __restrict__ Bt, int M, int N, int K, float* __restrict__ outF){
  __shared__ unsigned short lA[64][72];
  __shared__ unsigned short lB[64][72];
  int n0 = blockIdx.x * 64, m0 = blockIdx.y * 64;
  int t = threadIdx.x, w = t >> 6, l = t & 63;
  int wr = (w >> 1) * 32, wc = (w & 1) * 32;
  int lr = l & 15, kq = (l >> 4) * 8;
  facc acc00 = (facc)0.f, acc01 = (facc)0.f, acc10 = (facc)0.f, acc11 = (facc)0.f;
  for (int k0 = 0; k0 < K; k0 += 64){
    #pragma unroll
    for (int cc = 0; cc < 2; cc++){
      int ch = t + cc*256;
      int row = ch >> 3, cg = (ch & 7) * 8;
      *(bfrag*)&lA[row][cg] = *(const bfrag*)&A[(size_t)(m0 + row) * K + k0 + cg];
      *(bfrag*)&lB[row][cg] = *(const bfrag*)&Bt[(size_t)(n0 + row) * K + k0 + cg];
    }
    __syncthreads();
    #pragma unroll
    for (int ks = 0; ks < 2; ks++){
      bfrag a0 = *(const bfrag*)&lA[wr + lr][ks*32 + kq];
      bfrag a1 = *(const bfrag*)&lA[wr + 16 + lr][ks*32 + kq];
      bfrag b0 = *(const bfrag*)&lB[wc + lr][ks*32 + kq];
      bfrag b1 = *(const bfrag*)&lB[wc + 16 + lr][ks*32 + kq];
      acc00 = __builtin_amdgcn_mfma_f32_16x16x32_bf16(a0, b0, acc00, 0, 0, 0);
      acc01 = __builtin_amdgcn_mfma_f32_16x16x32_bf16(a0, b1, acc01, 0, 0, 0);
      acc10 = __builtin_amdgcn_mfma_f32_16x16x32_bf16(a1, b0, acc10, 0, 0, 0);
      acc11 = __builtin_amdgcn_mfma_f32_16x16x32_bf16(a1, b1, acc11, 0, 0, 0);
    }
    __syncthreads();
  }
  int rl = (l >> 4) * 4, cl = l & 15;
  facc accs[2][2] = {{acc00, acc01},{acc10, acc11}};
  #pragma unroll
  for (int mt = 0; mt < 2; mt++)
  #pragma unroll
  for (int nt = 0; nt < 2; nt++)
  #pragma unroll
  for (int j = 0; j < 4; j++){
    int r = m0 + wr + mt*16 + rl + j;
    int c = n0 + wc + nt*16 + cl;
    outF[(size_t)r * N + c] = accs[mt][nt][j];
  }
}

// ---- q GEMM with FUSED rmsnorm+gamma^2+1/8 epilogue -> qnb bf16 [B][H][SL][DH]
__global__ __launch_bounds__(256) void gemm_q(const unsigned short* __restrict__ A,
    const unsigned short* __restrict__ Bt, const float* __restrict__ gamma,
    unsigned short* __restrict__ qn){
  __shared__ char smemb[18432];          // lA/lB (2x 64x72 shorts) ; reused as Cf f32[64][66]
  unsigned short* lA = (unsigned short*)smemb;
  unsigned short* lB = lA + 64*72;
  float* Cf = (float*)smemb;             // 64*66*4 = 16896 <= 18432
  int h = blockIdx.x, n0 = h * 64, m0 = blockIdx.y * 64;
  int t = threadIdx.x, w = t >> 6, l = t & 63;
  int wr = (w >> 1) * 32, wc = (w & 1) * 32;
  int lr = l & 15, kq = (l >> 4) * 8;
  facc acc00 = (facc)0.f, acc01 = (facc)0.f, acc10 = (facc)0.f, acc11 = (facc)0.f;
  for (int k0 = 0; k0 < 1024; k0 += 64){
    #pragma unroll
    for (int cc = 0; cc < 2; cc++){
      int ch = t + cc*256;
      int row = ch >> 3, cg = (ch & 7) * 8;
      *(bfrag*)&lA[row*72 + cg] = *(const bfrag*)&A[(size_t)(m0 + row) * 1024 + k0 + cg];
      *(bfrag*)&lB[row*72 + cg] = *(const bfrag*)&Bt[(size_t)(n0 + row) * 1024 + k0 + cg];
    }
    __syncthreads();
    #pragma unroll
    for (int ks = 0; ks < 2; ks++){
      bfrag a0 = *(const bfrag*)&lA[(wr + lr)*72 + ks*32 + kq];
      bfrag a1 = *(const bfrag*)&lA[(wr + 16 + lr)*72 + ks*32 + kq];
      bfrag b0 = *(const bfrag*)&lB[(wc + lr)*72 + ks*32 + kq];
      bfrag b1 = *(const bfrag*)&lB[(wc + 16 + lr)*72 + ks*32 + kq];
      acc00 = __builtin_amdgcn_mfma_f32_16x16x32_bf16(a0, b0, acc00, 0, 0, 0);
      acc01 = __builtin_amdgcn_mfma_f32_16x16x32_bf16(a0, b1, acc01, 0, 0, 0);
      acc10 = __builtin_amdgcn_mfma_f32_16x16x32_bf16(a1, b0, acc10, 0, 0, 0);
      acc11 = __builtin_amdgcn_mfma_f32_16x16x32_bf16(a1, b1, acc11, 0, 0, 0);
    }
    __syncthreads();
  }
  int rl = (l >> 4) * 4, cl = l & 15;
  facc accs[2][2] = {{acc00, acc01},{acc10, acc11}};
  #pragma unroll
  for (int mt = 0; mt < 2; mt++)
  #pragma unroll
  for (int nt = 0; nt < 2; nt++)
  #pragma unroll
  for (int j = 0; j < 4; j++)
    Cf[(wr + mt*16 + rl + j)*66 + wc + nt*16 + cl] = accs[mt][nt][j];
  __syncthreads();
  if (t < 64){
    const float* src = &Cf[t*66];
    float ss = 0.f;
    #pragma unroll
    for (int d = 0; d < 64; d++){ float a = src[d]; ss = fmaf(a, a, ss); }
    float rv = 0.125f / fmaxf(sqrtf(ss) * 0.125f, 1e-8f);
    int r = m0 + t, b = r >> 8, sl = r & 255;
    unsigned short* dst = &qn[((size_t)(b*HH + h)*SLL + sl)*DHH];
    #pragma unroll
    for (int i = 0; i < 8; i++){
      ushort4 p; float g;
      g = gamma[i*8+0]; p.x = f2bf(src[i*8+0]*g*g*rv);
      g = gamma[i*8+1]; p.y = f2bf(src[i*8+1]*g*g*rv);
      g = gamma[i*8+2]; p.z = f2bf(src[i*8+2]*g*g*rv);
      g = gamma[i*8+3]; p.w = f2bf(src[i*8+3]*g*g*rv);
      ushort4 q;
      g = gamma[i*8+4]; q.x = f2bf(src[i*8+4]*g*g*rv);
      g = gamma[i*8+5]; q.y = f2bf(src[i*8+5]*g*g*rv);
      g = gamma[i*8+6]; q.z = f2bf(src[i*8+6]*g*g*rv);
      g = gamma[i*8+7]; q.w = f2bf(src[i*8+7]*g*g*rv);
      *(ushort4*)&dst[i*8]     = p;
      *(ushort4*)&dst[i*8 + 4] = q;
    }
  }
}

// ---- kv GEMM (R9 + mask folded into rkm sentinel: 1 coalesced load + cndmask in epilogue)
__global__ __launch_bounds__(256) void gemm_kv(const unsigned short* __restrict__ A,
    const unsigned short* __restrict__ Bt,
    const float* __restrict__ mask_x, const float* __restrict__ mask_lat,
    unsigned short* __restrict__ outK, unsigned short* __restrict__ outV,
    float* __restrict__ rkm){
  __shared__ unsigned short smem[128*136];   // 34816 B; K-loop uses first 2*128*64
  unsigned short* lA = smem;
  unsigned short* lB = smem + 128*64;
  int n0 = blockIdx.x * 128, m0 = blockIdx.y * 128;
  int t = threadIdx.x, w = t >> 6, l = t & 63;
  int wr = (w >> 1) * 64, wc = (w & 1) * 64;
  int lr = l & 15, q2 = l >> 4;
  int r8 = l >> 3, u = l & 7;
  facc acc[4][4];
  #pragma unroll
  for (int mt = 0; mt < 4; mt++)
  #pragma unroll
  for (int nt = 0; nt < 4; nt++) acc[mt][nt] = (facc)0.f;
  const unsigned short* Ab = A  + (size_t)(m0 + w*32 + r8) * 1024 + (u ^ (r8 & 7)) * 8;
  const unsigned short* Bb = Bt + (size_t)(n0 + w*32 + r8) * 1024 + (u ^ (r8 & 7)) * 8;
  for (int k0 = 0; k0 < 1024; k0 += 64){
    #pragma unroll
    for (int i = 0; i < 4; i++){
      GLOAD_LDS16(Ab + (size_t)i*8*1024 + k0, &lA[(w*32 + i*8)*64]);
      GLOAD_LDS16(Bb + (size_t)i*8*1024 + k0, &lB[(w*32 + i*8)*64]);
    }
    __syncthreads();
    #pragma unroll
    for (int ks = 0; ks < 2; ks++){
      int su = ((ks*4 + q2) ^ (lr & 7)) * 8;
      bfrag av[4], bv[4];
      #pragma unroll
      for (int mt = 0; mt < 4; mt++) av[mt] = *(const bfrag*)&lA[(wr + mt*16 + lr)*64 + su];
      #pragma unroll
      for (int nt = 0; nt < 4; nt++) bv[nt] = *(const bfrag*)&lB[(wc + nt*16 + lr)*64 + su];
      #pragma unroll
      for (int mt = 0; mt < 4; mt++)
      #pragma unroll
      for (int nt = 0; nt < 4; nt++)
        acc[mt][nt] = __builtin_amdgcn_mfma_f32_16x16x32_bf16(av[mt], bv[nt], acc[mt][nt], 0, 0, 0);
    }
    __syncthreads();
  }
  // epilogue: tiles never span batches (SKV = 34*128)
  int b = m0 / SKV, s0 = m0 - b*SKV;
  int rl = q2 * 4;
  if (blockIdx.x < 8){
    // K half: stage [s][c] (pad 136), per-thread full 128B line; ss -> rkm sentinel scalar
    #pragma unroll
    for (int mt = 0; mt < 4; mt++)
    #pragma unroll
    for (int nt = 0; nt < 4; nt++)
    #pragma unroll
    for (int j = 0; j < 4; j++)
      smem[(wr + mt*16 + rl + j)*136 + wc + nt*16 + lr] = f2bf(acc[mt][nt][j]);
    __syncthreads();
    int s = t >> 1, hf = t & 1;
    int srow = s0 + s;
    float cm = (srow < SXX) ? mask_x[b*SXX + srow] : mask_lat[b*SLL + srow - SXX];
    const unsigned short* src = &smem[s*136 + hf*64];
    uint4 wv[8];
    #pragma unroll
    for (int i = 0; i < 8; i++) wv[i] = *(const uint4*)&src[i*8];
    float ss0 = 0.f, ss1 = 0.f;
    #pragma unroll
    for (int i = 0; i < 8; i++){
      const unsigned short* pp = (const unsigned short*)&wv[i];
      #pragma unroll
      for (int e = 0; e < 4; e++){
        float a = bf2f(pp[e]);     ss0 = fmaf(a, a, ss0);
        float c = bf2f(pp[e + 4]); ss1 = fmaf(c, c, ss1);
      }
    }
    float rv = 1.f / fmaxf(sqrtf(ss0 + ss1) * 0.125f, 1e-8f);
    int h = (n0 >> 6) + hf;
    unsigned short* dst = &outK[((size_t)(b*HH + h)*SKV + srow)*DHH];
    #pragma unroll
    for (int i = 0; i < 8; i++)
      *(uint4*)&dst[i*8] = wv[i];
    rkm[((size_t)(b*HH + h))*SKV + srow] = (cm != 0.f) ? rv : -1.f;
  } else {
    // V half: stage [c][s] (pad 136; j contiguous -> b64 writes), 128B lines to vT
    #pragma unroll
    for (int mt = 0; mt < 4; mt++)
    #pragma unroll
    for (int nt = 0; nt < 4; nt++){
      ushort4 p;
      p.x = f2bf(acc[mt][nt][0]); p.y = f2bf(acc[mt][nt][1]);
      p.z = f2bf(acc[mt][nt][2]); p.w = f2bf(acc[mt][nt][3]);
      *(ushort4*)&smem[(wc + nt*16 + lr)*136 + wr + mt*16 + rl] = p;
    }
    __syncthreads();
    int c = t >> 1, hf = t & 1;
    int hh = ((n0 - DD) >> 6) + (c >> 6), d = c & 63;
    const unsigned short* src = &smem[c*136 + hf*64];
    unsigned short* dst = &outV[((size_t)(b*HH + hh)*DHH + d)*SKV + s0 + hf*64];
    #pragma unroll
    for (int i = 0; i < 8; i++)
      *(uint4*)&dst[i*8] = *(const uint4*)&src[i*8];
  }
}

// ---- flash attention, split-KV, 2 q-tiles/block, fixed-max softmax (s in [-8,8]).
// rkm carries the kv-mask sentinel; V fragments issued right after QK MFMAs to overlap.
__global__ __launch_bounds__(256) void attn(const unsigned short* __restrict__ qn,
    const unsigned short* __restrict__ kbuf, const unsigned short* __restrict__ vT,
    const float* __restrict__ rkm, const float* __restrict__ mask_lat,
    float* __restrict__ Opart, float* __restrict__ lpart){
  int qt = blockIdx.x, bh = blockIdx.y, split = blockIdx.z;
  int b = bh >> 4;
  __shared__ unsigned short lP[4][2][16][68];   // per-wave, per-tile P staging
  int t = threadIdx.x, w = t >> 6, l = t & 63;
  int lr = l & 15, q2 = l >> 4, kq = q2 * 8;
  int q0 = qt * 128;
  bfrag aq0[2], aq1[2];
  float rm[2][4];
  #pragma unroll
  for (int tt = 0; tt < 2; tt++){
    const unsigned short* qbase = qn + ((size_t)bh * SLL + q0 + tt*64 + w*16 + lr) * DHH;
    aq0[tt] = *(const bfrag*)&qbase[kq];
    aq1[tt] = *(const bfrag*)&qbase[32 + kq];
    #pragma unroll
    for (int j = 0; j < 4; j++) rm[tt][j] = mask_lat[b*SLL + q0 + tt*64 + w*16 + q2*4 + j];
  }
  facc O[2][4];
  #pragma unroll
  for (int tt = 0; tt < 2; tt++)
  #pragma unroll
  for (int nt = 0; nt < 4; nt++) O[tt][nt] = (facc)0.f;
  float lsum[2][4];
  #pragma unroll
  for (int tt = 0; tt < 2; tt++)
  #pragma unroll
  for (int j = 0; j < 4; j++) lsum[tt][j] = 0.f;

  int t0 = (split * 68) / NSPLIT, t1 = ((split + 1) * 68) / NSPLIT;
  for (int kt = t0; kt < t1; kt++){
    int key0 = kt * 64;
    const unsigned short* kb = kbuf + ((size_t)bh * SKV + key0) * DHH;
    bfrag bk0[4], bk1[4]; float rk[4];
    #pragma unroll
    for (int nt = 0; nt < 4; nt++){
      bk0[nt] = *(const bfrag*)&kb[(nt*16 + lr)*DHH + kq];
      bk1[nt] = *(const bfrag*)&kb[(nt*16 + lr)*DHH + 32 + kq];
      rk[nt]  = rkm[(size_t)bh*SKV + key0 + nt*16 + lr];   // <0 => masked key
    }
    facc S[2][4];
    #pragma unroll
    for (int tt = 0; tt < 2; tt++)
    #pragma unroll
    for (int nt = 0; nt < 4; nt++){
      S[tt][nt] = (facc)0.f;
      S[tt][nt] = __builtin_amdgcn_mfma_f32_16x16x32_bf16(aq0[tt], bk0[nt], S[tt][nt], 0, 0, 0);
      S[tt][nt] = __builtin_amdgcn_mfma_f32_16x16x32_bf16(aq1[tt], bk1[nt], S[tt][nt], 0, 0, 0);
    }
    // V fragments: independent of P -> issue now, consumed after softmax
    const unsigned short* vb = vT + (size_t)bh * DHH * SKV + key0;
    bfrag bv0[4], bv1[4];
    #pragma unroll
    for (int nt = 0; nt < 4; nt++){
      bv0[nt] = *(const bfrag*)&vb[(size_t)(nt*16 + lr)*SKV + kq];
      bv1[nt] = *(const bfrag*)&vb[(size_t)(nt*16 + lr)*SKV + 32 + kq];
    }
    #pragma unroll
    for (int tt = 0; tt < 2; tt++){
      #pragma unroll
      for (int j = 0; j < 4; j++){
        float rs_ = 0.f;
        #pragma unroll
        for (int nt = 0; nt < 4; nt++){
          float x = S[tt][nt][j] * rk[nt];
          float sv = (rk[nt] >= 0.f && rm[tt][j] != 0.f) ? x : -3.0e38f;
          float p = __expf(sv - 8.0f);
          rs_ += p;
          lP[w][tt][q2*4 + j][nt*16 + lr] = f2bf(p);
        }
        lsum[tt][j] += rs_;   // per-lane partial (16-lane reduce deferred)
      }
    }
    __asm__ volatile("s_waitcnt lgkmcnt(0)" ::: "memory");   // wave-private LDS round trip
    bfrag ap0[2], ap1[2];
    #pragma unroll
    for (int tt = 0; tt < 2; tt++){
      ap0[tt] = *(const bfrag*)&lP[w][tt][lr][kq];
      ap1[tt] = *(const bfrag*)&lP[w][tt][lr][32 + kq];
    }
    #pragma unroll
    for (int nt = 0; nt < 4; nt++){
      #pragma unroll
      for (int tt = 0; tt < 2; tt++){
        O[tt][nt] = __builtin_amdgcn_mfma_f32_16x16x32_bf16(ap0[tt], bv0[nt], O[tt][nt], 0, 0, 0);
        O[tt][nt] = __builtin_amdgcn_mfma_f32_16x16x32_bf16(ap1[tt], bv1[nt], O[tt][nt], 0, 0, 0);
      }
    }
  }
  #pragma unroll
  for (int tt = 0; tt < 2; tt++)
  #pragma unroll
  for (int j = 0; j < 4; j++){
    float L = lsum[tt][j];
    L += __shfl_xor(L, 1); L += __shfl_xor(L, 2);
    L += __shfl_xor(L, 4); L += __shfl_xor(L, 8);
    int srow = q0 + tt*64 + w*16 + q2*4 + j;
    size_t obase = (((size_t)split*64 + bh)*SLL + srow)*DHH;
    #pragma unroll
    for (int nt = 0; nt < 4; nt++)
      Opart[obase + nt*16 + lr] = O[tt][nt][j];
    if (lr == 0)
      lpart[((size_t)split*64 + bh)*SLL + srow] = L;
  }
}

// ---- combine partials across splits (fixed-max: plain sums) -> ybuf bf16 [B][SL][D]
__global__ __launch_bounds__(256) void attn_combine(const float* __restrict__ Opart,
    const float* __restrict__ lpart, unsigned short* __restrict__ ybuf){
  int t = threadIdx.x, w = t >> 6, l = t & 63;
  int idx = blockIdx.x * 4 + w;
  int bh = idx >> 8, srow = idx & 255;
  int b = bh >> 4, h = bh & 15;
  float L = 0.f, acc = 0.f;
  #pragma unroll
  for (int s = 0; s < NSPLIT; s++){
    L   += lpart[((size_t)s*64 + bh)*SLL + srow];
    acc += Opart[(((size_t)s*64 + bh)*SLL + srow)*DHH + l];
  }
  ybuf[((size_t)b*SLL + srow)*DD + h*DHH + l] = f2bf(acc / L);
}

extern "C" void kernel_launch(void* const* d_in, const int* in_sizes, int n_in,
                              void* d_out, int out_size, void* d_ws, size_t ws_size,
                              hipStream_t stream) {
  const float* x        = (const float*)d_in[0];
  const float* latents  = (const float*)d_in[1];
  const float* mask_x   = (const float*)d_in[2];
  const float* mask_lat = (const float*)d_in[3];
  const float* ln_x_g   = (const float*)d_in[4];
  const float* ln_x_b   = (const float*)d_in[5];
  const float* ln_l_g   = (const float*)d_in[6];
  const float* ln_l_b   = (const float*)d_in[7];
  const float* Wq       = (const float*)d_in[8];
  const float* Wkv      = (const float*)d_in[9];
  const float* qk_gamma = (const float*)d_in[10];
  const float* Wo       = (const float*)d_in[11];
  float* out = (float*)d_out;

  // ws layout (~127 MB). Opart/lpart ALIAS kvin/lnlat (dead once attn runs).
  char* wsb = (char*)d_ws;
  unsigned short* kvin  = (unsigned short*)(wsb + 0);          // [MKV][D] bf16       35651584
  unsigned short* lnlat = (unsigned short*)(wsb + 35651584);   // [B*SL][D] bf16       2097152
  unsigned short* wqt   = (unsigned short*)(wsb + 37748736);   // [D][D] bf16          2097152
  unsigned short* wkvt  = (unsigned short*)(wsb + 39845888);   // [2D][D] bf16         4194304
  unsigned short* wot   = (unsigned short*)(wsb + 44040192);   // [D][D] bf16          2097152
  unsigned short* qnb   = (unsigned short*)(wsb + 50331648);   // [B][H][SL][DH]       2097152
  unsigned short* kbuf  = (unsigned short*)(wsb + 52428800);   // [B][H][SKV][DH]     35651584
  unsigned short* vT    = (unsigned short*)(wsb + 88080384);   // [B][H][DH][SKV]     35651584
  float*          rkm   = (float*)(wsb + 123731968);           // [B*H*SKV] f32        1114112
  unsigned short* ybuf  = (unsigned short*)(wsb + 124846080);  // [B*SL][D] bf16       2097152
  float*          Opart = (float*)(wsb + 0);                   // [8][64][256][64] f32 33554432 (alias kvin)
  float*          lpart = (float*)(wsb + 35651584);            // [8][64][256] f32      524288 (alias lnlat)

  wtrans3<<<dim3(64, 32, 3), dim3(32, 8), 0, stream>>>(Wq, Wkv, Wo, wqt, wkvt, wot);

  lnorm<<<NB*SXX, 256, 0, stream>>>(x,       ln_x_g, ln_x_b, kvin, nullptr, SXX, 0);
  lnorm<<<NB*SLL, 256, 0, stream>>>(latents, ln_l_g, ln_l_b, kvin, lnlat,   SLL, SXX);

  gemm_q<<<dim3(16, 16), 256, 0, stream>>>(lnlat, wqt, qk_gamma, qnb);
  gemm_kv<<<dim3(16, 136), 256, 0, stream>>>(kvin, wkvt, mask_x, mask_lat, kbuf, vT, rkm);

  attn<<<dim3(SLL/128, NB*HH, NSPLIT), 256, 0, stream>>>(qnb, kbuf, vT, rkm, mask_lat, Opart, lpart);
  attn_combine<<<(NB*HH*SLL)/4, 256, 0, stream>>>(Opart, lpart, ybuf);

  gemm64<<<dim3(DD/64, (NB*SLL)/64), 256, 0, stream>>>(ybuf, wot, NB*SLL, DD, DD, out);
}